// Round 20
// baseline (1788.775 us; speedup 1.0000x reference)
//
#include <hip/hip_runtime.h>

#define NFEAT 20
#define EFEAT 20
#define HID   64
#define NENV  16
#define NNODES 5000
#define NEDGES 50000
#define E2 (2*NEDGES)          // 100000 directed edges
#define ITERS 3
#define ROWS 64                // edge rows per tile
#define NCHUNK 4               // tiles per block (sequential)
#define SPAN (ROWS*NCHUNK)     // 256 rows per block
#define THREADS 128            // 2 waves; wave w owns rows [w*32, w*32+32) of each tile
#define NPAD 24                // padded per-node fp16 row (20 + 4 junk) = 3 x 8-chunks

typedef __attribute__((ext_vector_type(8))) _Float16 f16x8;
typedef __attribute__((ext_vector_type(2))) __fp16  h16x2;   // builtin return type
typedef __attribute__((ext_vector_type(4))) float f32x4;

__device__ __forceinline__ ushort f2h(float f) {   // f32 -> fp16 RNE
    _Float16 h = (_Float16)f;
    return *(ushort*)&h;
}
__device__ __forceinline__ unsigned pk2h(float a, float b) {  // 2xf32 -> packed fp16 (RTZ)
    h16x2 p = __builtin_amdgcn_cvt_pkrtz(a, b);
    return *(unsigned*)&p;
}
// tanh = 1 - 2/(exp(2x)+1); exact limits at +-inf, no clamps. ~5 VALU ops.
__device__ __forceinline__ float fast_tanh(float x) {
    float e = __builtin_exp2f(x * 2.8853900817779268f);   // exp(2x)
    float r = __builtin_amdgcn_rcpf(e + 1.f);
    return fmaf(-2.f, r, 1.f);
}
__device__ __forceinline__ float fast_sigmoid(float x) {
    float e = __builtin_exp2f(x * -1.4426950408889634f);  // exp(-x)
    return __builtin_amdgcn_rcpf(1.f + e);
}

// ---------- edge preprocessing: group directed edges by src (once/launch) ----------
__global__ __launch_bounds__(256) void hist_kernel(const int* __restrict__ edges,
                                                   int* __restrict__ cnt) {
    int e = blockIdx.x * 256 + threadIdx.x;
    if (e < E2) atomicAdd(&cnt[edges[e]], 1);
}

__global__ __launch_bounds__(256) void scan_kernel(const int* __restrict__ cnt,
                                                   int* __restrict__ cursor) {
    __shared__ int part[256];
    int t = threadIdx.x;
    int local[20]; int s = 0;
    int base = t * 20;                      // 256*20 = 5120 >= 5000
    #pragma unroll
    for (int i = 0; i < 20; i++) {
        int idx = base + i;
        int v = (idx < NNODES) ? cnt[idx] : 0;
        local[i] = s; s += v;
    }
    part[t] = s;
    __syncthreads();
    for (int d = 1; d < 256; d <<= 1) {     // Hillis-Steele inclusive scan
        int v = (t >= d) ? part[t - d] : 0;
        __syncthreads();
        part[t] += v;
        __syncthreads();
    }
    int excl = part[t] - s;
    #pragma unroll
    for (int i = 0; i < 20; i++) {
        int idx = base + i;
        if (idx < NNODES) cursor[idx] = excl + local[i];
    }
}

// emits src-sorted node-id arrays: snode[pos], dnode[pos] (shared by all envs)
__global__ __launch_bounds__(256) void scatter_kernel(const int* __restrict__ edges,
                                                      int* __restrict__ cursor,
                                                      int* __restrict__ snode,
                                                      int* __restrict__ dnode) {
    int e = blockIdx.x * 256 + threadIdx.x;
    if (e < E2) {
        int s = edges[e];
        int di = e + NEDGES; if (di >= E2) di -= E2;
        int d = edges[di];
        int pos = atomicAdd(&cursor[s], 1);
        snode[pos] = s;
        dnode[pos] = d;
    }
}

// Weights -> fp16, layout [out][k], K padded to 64. Grid-stride (16 blocks).
// W1 K-layout matches padded X rows: k<20 = src feats, 24<=k<44 = dst feats, else 0.
__global__ __launch_bounds__(256) void prep_weights(
    const float* __restrict__ W1, const float* __restrict__ W2,
    const float* __restrict__ W3,
    ushort* __restrict__ W1p, ushort* __restrict__ W2p,
    ushort* __restrict__ W3p) {
    int stride = gridDim.x * 256;
    int t0 = blockIdx.x * 256 + threadIdx.x;
    for (int i = t0; i < 64 * 64; i += stride) {
        int n = i >> 6, k = i & 63;
        float v = 0.f;
        if (k < NFEAT)                          v = W1[n * (2 * NFEAT) + k];
        else if (k >= NPAD && k < NPAD + NFEAT) v = W1[n * (2 * NFEAT) + NFEAT + (k - NPAD)];
        W1p[i] = f2h(v);
    }
    for (int i = t0; i < 64 * 64; i += stride)
        W2p[i] = f2h(W2[i]);
    for (int i = t0; i < 32 * 64; i += stride) {
        int n = i >> 6, k = i & 63;
        W3p[i] = (n < EFEAT) ? f2h(W3[n * HID + k]) : (ushort)0;
    }
}

// Initial per-node fp16 conversion (iteration 0); later iters from gru_kernel.
__global__ __launch_bounds__(256) void conv_nf(const float* __restrict__ nf,
                                               ushort* __restrict__ nfp) {
    int gid = blockIdx.x * 256 + threadIdx.x;
    if (gid >= NENV * NNODES) return;
    const float* p = nf + (size_t)gid * NFEAT;
    ushort* ph = nfp + (size_t)gid * NPAD;
    #pragma unroll
    for (int k = 0; k < NFEAT; k++) ph[k] = f2h(p[k]);
    *(uint2*)(ph + NFEAT) = make_uint2(0u, 0u);         // zero pad cols 20..23
}

// Each 128-thread block (2 waves) processes NCHUNK=4 sequential tiles of 64
// sorted edge-rows (256 rows total; grid 6250 exact, no tail). Wave w owns
// rows [w*32,w*32+32) of each tile — wave-local LDS => NO barriers.
// __launch_bounds__(128,8) caps VGPR at 64: weight frags CANNOT be hoisted
// across the chunk loop (reloaded per chunk, L1-hot) — clean A/B vs round 17
// isolating block count (25000 -> 6250) at unchanged per-wave resources.
// Body = round-15/17 verified: swapped fp16 MFMA (A=W, B=X^T), packed
// cvt_pkrtz epilogues, LDS msg overlay + coalesced segmented atomic flush.
__global__ __launch_bounds__(THREADS, 8) void edge_mlp_mfma(
    const ushort* __restrict__ nfp,
    const int*   __restrict__ snode, const int* __restrict__ dnode,
    const ushort* __restrict__ W1p, const ushort* __restrict__ W2p,
    const ushort* __restrict__ W3p,
    const float* __restrict__ b1, const float* __restrict__ b2,
    const float* __restrict__ b3,
    float* __restrict__ store)
{
    __shared__ ushort smem16[4096];               // 8 KB
    ushort* Hp = smem16;                          // H plane: [64 rows][64 cols] fp16, swizzled
    float*  msgf = (float*)smem16;                // GEMM3 overlay, per-wave 4 KB slice
    int*    msgi = (int*)smem16;                  // int view (keys)

    const int tid  = threadIdx.x;
    const int wave = tid >> 6;
    const int lane = tid & 63;
    const int lr   = lane & 15;      // A-row(=out) / B-col(=edge-row) in tile; C-col
    const int kg   = lane >> 4;      // k-group for A/B; C row-group (out-group)
    const int i_   = lane & 31;
    const int m0   = wave * 32;

#define MFMA2(acc, w0, w1, x0, x1)                                                  \
    acc = __builtin_amdgcn_mfma_f32_16x16x32_f16(w0, x0, acc, 0, 0, 0);             \
    acc = __builtin_amdgcn_mfma_f32_16x16x32_f16(w1, x1, acc, 0, 0, 0);

    // packed epilogue: 4 outs (m*16+kg*4+r) of row rr -> one b64 write
#define STORE_H4(accv, m_, rr_)                                                     \
    {                                                                               \
        float t0 = fast_tanh(accv[0]), t1 = fast_tanh(accv[1]);                     \
        float t2 = fast_tanh(accv[2]), t3 = fast_tanh(accv[3]);                     \
        unsigned p01 = pk2h(t0, t1), p23 = pk2h(t2, t3);                            \
        int c8 = (m_) * 2 + (kg >> 1);                                              \
        int idx = (rr_) * 64 + ((c8 ^ ((rr_) & 7)) << 3) + ((kg & 1) << 2);         \
        *(uint2*)(Hp + idx) = make_uint2(p01, p23);                                 \
    }

    for (int it = 0; it < NCHUNK; ++it) {
        const int base = blockIdx.x * SPAN + it * ROWS;

        // ---- GEMM1 (swapped): W1 @ X^T -> tanh -> H1[edge-row][out] (LDS) ----
        {
            f16x8 wp[4][2];
            f32x4 bb[4];
            #pragma unroll
            for (int m = 0; m < 4; m++) {
                #pragma unroll
                for (int kt = 0; kt < 2; kt++)
                    wp[m][kt] = *(const f16x8*)(W1p + (m * 16 + lr) * 64 + kt * 32 + kg * 8);
                bb[m] = *(const f32x4*)(b1 + m * 16 + kg * 4);
            }
            #pragma unroll
            for (int n = 0; n < 2; n++) {
                int rr = m0 + n * 16 + lr;
                int gr = base + rr;
                int env = gr / E2;
                int sr  = gr - env * E2;
                const ushort* sp_ = nfp + (size_t)(env * NNODES + snode[sr]) * NPAD;
                const ushort* dp_ = nfp + (size_t)(env * NNODES + dnode[sr]) * NPAD;
                f16x8 x0, x1;
                if (kg < 3) x0 = *(const f16x8*)(sp_ + kg * 8);
                else        x0 = *(const f16x8*)(dp_);
                if (kg < 2) x1 = *(const f16x8*)(dp_ + 8 + kg * 8);
                else        x1 = f16x8{(_Float16)0,(_Float16)0,(_Float16)0,(_Float16)0,
                                       (_Float16)0,(_Float16)0,(_Float16)0,(_Float16)0};
                f32x4 acc[4];
                #pragma unroll
                for (int m = 0; m < 4; m++) {
                    acc[m] = bb[m];
                    MFMA2(acc[m], wp[m][0], wp[m][1], x0, x1)
                }
                #pragma unroll
                for (int m = 0; m < 4; m++) STORE_H4(acc[m], m, rr)
            }
        }

        // ---- GEMM2 (swapped): W2 @ H1^T -> tanh -> H2 (in place) ----
        {
            f16x8 wp[4][2];
            f32x4 bb[4];
            #pragma unroll
            for (int m = 0; m < 4; m++) {
                #pragma unroll
                for (int kt = 0; kt < 2; kt++)
                    wp[m][kt] = *(const f16x8*)(W2p + (m * 16 + lr) * 64 + kt * 32 + kg * 8);
                bb[m] = *(const f32x4*)(b2 + m * 16 + kg * 4);
            }
            #pragma unroll
            for (int n = 0; n < 2; n++) {
                int rr = m0 + n * 16 + lr, sw = rr & 7;
                f16x8 x0 = *(const f16x8*)(Hp + rr * 64 + ((kg ^ sw) << 3));
                f16x8 x1 = *(const f16x8*)(Hp + rr * 64 + (((4 + kg) ^ sw) << 3));
                f32x4 acc[4];
                #pragma unroll
                for (int m = 0; m < 4; m++) {
                    acc[m] = bb[m];
                    MFMA2(acc[m], wp[m][0], wp[m][1], x0, x1)
                }
                #pragma unroll
                for (int m = 0; m < 4; m++) STORE_H4(acc[m], m, rr)
            }
        }

        // ---- GEMM3 (swapped) + segmented reduction ----
        {
            int gr_i  = base + m0 + i_;
            int env_i = gr_i / E2;
            int sr_i  = gr_i - env_i * E2;
            int key   = env_i * NNODES + snode[sr_i];        // full store row id

            f16x8 w3[2][2];
            #pragma unroll
            for (int m = 0; m < 2; m++)
                #pragma unroll
                for (int kt = 0; kt < 2; kt++)
                    w3[m][kt] = *(const f16x8*)(W3p + (m * 16 + lr) * 64 + kt * 32 + kg * 8);
            f32x4 bb0 = *(const f32x4*)(b3 + kg * 4);        // outs kg*4+r (<16)
            f32x4 bb1 = (kg == 0) ? *(const f32x4*)(b3 + 16) // outs 16..19
                                  : f32x4{0.f, 0.f, 0.f, 0.f};

            // load ALL B-frags first (msg overlay overwrites this wave's H rows)
            f16x8 xb[2][2];
            #pragma unroll
            for (int n = 0; n < 2; n++) {
                int rr = m0 + n * 16 + lr, sw = rr & 7;
                xb[n][0] = *(const f16x8*)(Hp + rr * 64 + ((kg ^ sw) << 3));
                xb[n][1] = *(const f16x8*)(Hp + rr * 64 + (((4 + kg) ^ sw) << 3));
            }
            f32x4 acc0[2], acc1[2];
            #pragma unroll
            for (int n = 0; n < 2; n++) {
                acc0[n] = bb0;
                MFMA2(acc0[n], w3[0][0], w3[0][1], xb[n][0], xb[n][1])
                acc1[n] = bb1;
                MFMA2(acc1[n], w3[1][0], w3[1][1], xb[n][0], xb[n][1])
            }

            // msg staging: [32 rows][stride 32 f32] per wave, b128 writes,
            // col-group swizzle g' = g ^ (row&7); key at group 5.
            int wbase = wave * 1024;                         // f32 words
            #pragma unroll
            for (int n = 0; n < 2; n++) {
                int row = n * 16 + lr;
                int g0 = kg ^ (row & 7);
                *(f32x4*)(msgf + wbase + row * 32 + (g0 << 2)) = acc0[n];
                if (kg == 0) {
                    int g1 = 4 ^ (row & 7);
                    *(f32x4*)(msgf + wbase + row * 32 + (g1 << 2)) = acc1[n];
                }
            }
            if (lane < 32) msgi[wbase + i_ * 32 + ((5 ^ (i_ & 7)) << 2)] = key;

            // segment-boundary flags (FULL exec: shfl/ballot legal here)
            int nxt = __shfl_down(key, 1);
            bool flag = (i_ == 31) || (key != nxt);
            unsigned fm = (unsigned)__ballot(flag);          // bits 0..31 valid

            if (lane < EFEAT) {
                int c = lane, g = c >> 2, o = c & 3;
                float sum = 0.f;
                for (int i = 0; i < 32; i++) {
                    sum += msgf[wbase + i * 32 + ((g ^ (i & 7)) << 2) + o];
                    if ((fm >> i) & 1u) {
                        int curk = msgi[wbase + i * 32 + ((5 ^ (i & 7)) << 2)];
                        atomicAdd(store + (size_t)curk * EFEAT + c, sum);
                        sum = 0.f;
                    }
                }
            }
        }
    }
#undef STORE_H4
#undef MFMA2
}

// GRU single step per (env,node); emits f32 nf AND next iteration's fp16 row.
// Also ZEROES its store row after reading (replaces the per-iteration memset).
__global__ __launch_bounds__(256) void gru_kernel(
    float* __restrict__ store,
    const float* __restrict__ Wih, const float* __restrict__ bih,
    const float* __restrict__ Whh, const float* __restrict__ bhh,
    float* __restrict__ nf,
    ushort* __restrict__ nfp)
{
    int gid = blockIdx.x * blockDim.x + threadIdx.x;
    const int total = NENV * NNODES;
    if (gid >= total) return;

    float*       s = store + (size_t)gid * EFEAT;
    float*       h = nf    + (size_t)gid * NFEAT;
    ushort*     ph = nfp   + (size_t)gid * NPAD;

    float sv[EFEAT], hv[NFEAT];
    #pragma unroll
    for (int k = 0; k < EFEAT; k++) sv[k] = s[k];
    #pragma unroll
    for (int k = 0; k < NFEAT; k++) hv[k] = h[k];

    // zero this node's store row for the next iteration (5 x float4 = 80 B)
    {
        float4 z = make_float4(0.f, 0.f, 0.f, 0.f);
        #pragma unroll
        for (int q = 0; q < 5; q++) *(float4*)(s + q * 4) = z;
    }

    for (int t = 0; t < NFEAT; t++) {
        float ir = bih[t],            hr = bhh[t];
        float iz = bih[NFEAT + t],    hz = bhh[NFEAT + t];
        float in_ = bih[2*NFEAT + t], hn = bhh[2*NFEAT + t];
        const float* wr = Wih + t * EFEAT;
        const float* wz = Wih + (NFEAT + t) * EFEAT;
        const float* wn = Wih + (2*NFEAT + t) * EFEAT;
        #pragma unroll
        for (int k = 0; k < EFEAT; k++) {
            ir  = fmaf(sv[k], wr[k], ir);
            iz  = fmaf(sv[k], wz[k], iz);
            in_ = fmaf(sv[k], wn[k], in_);
        }
        const float* vr = Whh + t * NFEAT;
        const float* vz = Whh + (NFEAT + t) * NFEAT;
        const float* vn = Whh + (2*NFEAT + t) * NFEAT;
        #pragma unroll
        for (int k = 0; k < NFEAT; k++) {
            hr = fmaf(hv[k], vr[k], hr);
            hz = fmaf(hv[k], vz[k], hz);
            hn = fmaf(hv[k], vn[k], hn);
        }
        float r = fast_sigmoid(ir + hr);
        float z = fast_sigmoid(iz + hz);
        float n = fast_tanh(in_ + r * hn);
        float hw = (1.f - z) * n + z * hv[t];
        h[t] = hw;
        ph[t] = f2h(hw);
    }
    *(uint2*)(ph + NFEAT) = make_uint2(0u, 0u);
}

extern "C" void kernel_launch(void* const* d_in, const int* in_sizes, int n_in,
                              void* d_out, int out_size, void* d_ws, size_t ws_size,
                              hipStream_t stream) {
    const float* nf_in = (const float*)d_in[0];
    const int*   edges = (const int*)d_in[1];
    const float* W1 = (const float*)d_in[2];
    const float* b1 = (const float*)d_in[3];
    const float* W2 = (const float*)d_in[4];
    const float* b2 = (const float*)d_in[5];
    const float* W3 = (const float*)d_in[6];
    const float* b3 = (const float*)d_in[7];
    const float* Wih = (const float*)d_in[8];
    const float* Whh = (const float*)d_in[9];
    const float* bih = (const float*)d_in[10];
    const float* bhh = (const float*)d_in[11];

    float* nf    = (float*)d_out;
    float* store = (float*)d_ws;
    const size_t nf_bytes    = (size_t)NENV * NNODES * NFEAT * sizeof(float);
    const size_t store_bytes = (size_t)NENV * NNODES * EFEAT * sizeof(float);
    // ws layout: store | W fp16 | nfp | cnt | cursor | snode | dnode  (~11 MB)
    ushort* W1p = (ushort*)((char*)d_ws + store_bytes);
    ushort* W2p = W1p + 64 * 64;
    ushort* W3p = W2p + 64 * 64;
    ushort* nfp = W3p + 32 * 64;
    int* cnt    = (int*)(nfp + (size_t)NENV * NNODES * NPAD);
    int* cursor = cnt + NNODES;
    int* snode  = cursor + NNODES;
    int* dnode  = snode + E2;

    // --- once per launch: weights, initial conversion, edge grouping by src ---
    prep_weights<<<16, 256, 0, stream>>>(W1, W2, W3, W1p, W2p, W3p);
    conv_nf<<<(NENV * NNODES + 255) / 256, 256, 0, stream>>>(nf_in, nfp);
    hipMemcpyAsync(nf, nf_in, nf_bytes, hipMemcpyDeviceToDevice, stream);
    hipMemsetAsync(cnt, 0, NNODES * sizeof(int), stream);
    hipMemsetAsync(store, 0, store_bytes, stream);        // once; GRU re-zeros after
    hist_kernel<<<(E2 + 255) / 256, 256, 0, stream>>>(edges, cnt);
    scan_kernel<<<1, 256, 0, stream>>>(cnt, cursor);
    scatter_kernel<<<(E2 + 255) / 256, 256, 0, stream>>>(edges, cursor, snode, dnode);

    const int edge_blocks = (NENV * E2) / SPAN;           // 6250, exact
    dim3 grid_n((NENV * NNODES + 255) / 256);

    for (int it = 0; it < ITERS; it++) {
        edge_mlp_mfma<<<edge_blocks, THREADS, 0, stream>>>(nfp, snode, dnode,
                                                           W1p, W2p, W3p,
                                                           b1, b2, b3, store);
        gru_kernel<<<grid_n, 256, 0, stream>>>(store, Wih, bih, Whh, bhh, nf, nfp);
    }
}

// Round 21
// 613.093 us; speedup vs baseline: 2.9176x; 2.9176x over previous
//
#include <hip/hip_runtime.h>

#define NFEAT 20
#define EFEAT 20
#define HID   64
#define NENV  16
#define NNODES 5000
#define NEDGES 50000
#define E2 (2*NEDGES)          // 100000 directed edges
#define ITERS 3
#define ROWS 64                // edge rows per tile
#define NCHUNK 4               // tiles per block (sequential)
#define SPAN (ROWS*NCHUNK)     // 256 rows per block
#define THREADS 128            // 2 waves; wave w owns rows [w*32, w*32+32) of each tile
#define NPAD 24                // padded per-node fp16 row (20 + 4 junk) = 3 x 8-chunks

typedef __attribute__((ext_vector_type(8))) _Float16 f16x8;
typedef __attribute__((ext_vector_type(2))) __fp16  h16x2;   // builtin return type
typedef __attribute__((ext_vector_type(4))) float f32x4;

__device__ __forceinline__ ushort f2h(float f) {   // f32 -> fp16 RNE
    _Float16 h = (_Float16)f;
    return *(ushort*)&h;
}
__device__ __forceinline__ unsigned pk2h(float a, float b) {  // 2xf32 -> packed fp16 (RTZ)
    h16x2 p = __builtin_amdgcn_cvt_pkrtz(a, b);
    return *(unsigned*)&p;
}
// tanh = 1 - 2/(exp(2x)+1); exact limits at +-inf, no clamps. ~5 VALU ops.
__device__ __forceinline__ float fast_tanh(float x) {
    float e = __builtin_exp2f(x * 2.8853900817779268f);   // exp(2x)
    float r = __builtin_amdgcn_rcpf(e + 1.f);
    return fmaf(-2.f, r, 1.f);
}
__device__ __forceinline__ float fast_sigmoid(float x) {
    float e = __builtin_exp2f(x * -1.4426950408889634f);  // exp(-x)
    return __builtin_amdgcn_rcpf(1.f + e);
}

// ---------- edge preprocessing: group directed edges by src (once/launch) ----------
__global__ __launch_bounds__(256) void hist_kernel(const int* __restrict__ edges,
                                                   int* __restrict__ cnt) {
    int e = blockIdx.x * 256 + threadIdx.x;
    if (e < E2) atomicAdd(&cnt[edges[e]], 1);
}

__global__ __launch_bounds__(256) void scan_kernel(const int* __restrict__ cnt,
                                                   int* __restrict__ cursor) {
    __shared__ int part[256];
    int t = threadIdx.x;
    int local[20]; int s = 0;
    int base = t * 20;                      // 256*20 = 5120 >= 5000
    #pragma unroll
    for (int i = 0; i < 20; i++) {
        int idx = base + i;
        int v = (idx < NNODES) ? cnt[idx] : 0;
        local[i] = s; s += v;
    }
    part[t] = s;
    __syncthreads();
    for (int d = 1; d < 256; d <<= 1) {     // Hillis-Steele inclusive scan
        int v = (t >= d) ? part[t - d] : 0;
        __syncthreads();
        part[t] += v;
        __syncthreads();
    }
    int excl = part[t] - s;
    #pragma unroll
    for (int i = 0; i < 20; i++) {
        int idx = base + i;
        if (idx < NNODES) cursor[idx] = excl + local[i];
    }
}

// emits src-sorted node-id arrays: snode[pos], dnode[pos] (shared by all envs)
__global__ __launch_bounds__(256) void scatter_kernel(const int* __restrict__ edges,
                                                      int* __restrict__ cursor,
                                                      int* __restrict__ snode,
                                                      int* __restrict__ dnode) {
    int e = blockIdx.x * 256 + threadIdx.x;
    if (e < E2) {
        int s = edges[e];
        int di = e + NEDGES; if (di >= E2) di -= E2;
        int d = edges[di];
        int pos = atomicAdd(&cursor[s], 1);
        snode[pos] = s;
        dnode[pos] = d;
    }
}

// Weights -> fp16, layout [out][k], K padded to 64. Grid-stride (16 blocks).
// W1 K-layout matches padded X rows: k<20 = src feats, 24<=k<44 = dst feats, else 0.
__global__ __launch_bounds__(256) void prep_weights(
    const float* __restrict__ W1, const float* __restrict__ W2,
    const float* __restrict__ W3,
    ushort* __restrict__ W1p, ushort* __restrict__ W2p,
    ushort* __restrict__ W3p) {
    int stride = gridDim.x * 256;
    int t0 = blockIdx.x * 256 + threadIdx.x;
    for (int i = t0; i < 64 * 64; i += stride) {
        int n = i >> 6, k = i & 63;
        float v = 0.f;
        if (k < NFEAT)                          v = W1[n * (2 * NFEAT) + k];
        else if (k >= NPAD && k < NPAD + NFEAT) v = W1[n * (2 * NFEAT) + NFEAT + (k - NPAD)];
        W1p[i] = f2h(v);
    }
    for (int i = t0; i < 64 * 64; i += stride)
        W2p[i] = f2h(W2[i]);
    for (int i = t0; i < 32 * 64; i += stride) {
        int n = i >> 6, k = i & 63;
        W3p[i] = (n < EFEAT) ? f2h(W3[n * HID + k]) : (ushort)0;
    }
}

// Initial per-node fp16 conversion (iteration 0); later iters from gru_kernel.
__global__ __launch_bounds__(256) void conv_nf(const float* __restrict__ nf,
                                               ushort* __restrict__ nfp) {
    int gid = blockIdx.x * 256 + threadIdx.x;
    if (gid >= NENV * NNODES) return;
    const float* p = nf + (size_t)gid * NFEAT;
    ushort* ph = nfp + (size_t)gid * NPAD;
    #pragma unroll
    for (int k = 0; k < NFEAT; k++) ph[k] = f2h(p[k]);
    *(uint2*)(ph + NFEAT) = make_uint2(0u, 0u);         // zero pad cols 20..23
}

// Each 128-thread block (2 waves) processes NCHUNK=4 sequential tiles of 64
// sorted edge-rows (grid 25000 -> 6250 blocks, exact). Wave w owns rows
// [w*32,w*32+32) of each tile — wave-local LDS => NO barriers.
// NO min-waves launch bound (R20's VGPR-32 spill disaster); instead an asm
// memory barrier per chunk stops the compiler hoisting weight-fragment loads
// across chunks (R19's VGPR-120 balloon). Allocator stays at the R17 body's
// natural ~56-70 VGPR. R20 proved fewer/longer blocks lift occupancy 42->82%.
// Body = round-15/17 verified: swapped fp16 MFMA (A=W, B=X^T), packed
// cvt_pkrtz epilogues, LDS msg overlay + coalesced segmented atomic flush.
__global__ __launch_bounds__(THREADS) void edge_mlp_mfma(
    const ushort* __restrict__ nfp,
    const int*   __restrict__ snode, const int* __restrict__ dnode,
    const ushort* __restrict__ W1p, const ushort* __restrict__ W2p,
    const ushort* __restrict__ W3p,
    const float* __restrict__ b1, const float* __restrict__ b2,
    const float* __restrict__ b3,
    float* __restrict__ store)
{
    __shared__ ushort smem16[4096];               // 8 KB
    ushort* Hp = smem16;                          // H plane: [64 rows][64 cols] fp16, swizzled
    float*  msgf = (float*)smem16;                // GEMM3 overlay, per-wave 4 KB slice
    int*    msgi = (int*)smem16;                  // int view (keys)

    const int tid  = threadIdx.x;
    const int wave = tid >> 6;
    const int lane = tid & 63;
    const int lr   = lane & 15;      // A-row(=out) / B-col(=edge-row) in tile; C-col
    const int kg   = lane >> 4;      // k-group for A/B; C row-group (out-group)
    const int i_   = lane & 31;
    const int m0   = wave * 32;

#define MFMA2(acc, w0, w1, x0, x1)                                                  \
    acc = __builtin_amdgcn_mfma_f32_16x16x32_f16(w0, x0, acc, 0, 0, 0);             \
    acc = __builtin_amdgcn_mfma_f32_16x16x32_f16(w1, x1, acc, 0, 0, 0);

    // packed epilogue: 4 outs (m*16+kg*4+r) of row rr -> one b64 write
#define STORE_H4(accv, m_, rr_)                                                     \
    {                                                                               \
        float t0 = fast_tanh(accv[0]), t1 = fast_tanh(accv[1]);                     \
        float t2 = fast_tanh(accv[2]), t3 = fast_tanh(accv[3]);                     \
        unsigned p01 = pk2h(t0, t1), p23 = pk2h(t2, t3);                            \
        int c8 = (m_) * 2 + (kg >> 1);                                              \
        int idx = (rr_) * 64 + ((c8 ^ ((rr_) & 7)) << 3) + ((kg & 1) << 2);         \
        *(uint2*)(Hp + idx) = make_uint2(p01, p23);                                 \
    }

    for (int it = 0; it < NCHUNK; ++it) {
        asm volatile("" ::: "memory");   // chunk fence: no load hoisting across chunks
        const int base = blockIdx.x * SPAN + it * ROWS;

        // ---- GEMM1 (swapped): W1 @ X^T -> tanh -> H1[edge-row][out] (LDS) ----
        {
            f16x8 wp[4][2];
            f32x4 bb[4];
            #pragma unroll
            for (int m = 0; m < 4; m++) {
                #pragma unroll
                for (int kt = 0; kt < 2; kt++)
                    wp[m][kt] = *(const f16x8*)(W1p + (m * 16 + lr) * 64 + kt * 32 + kg * 8);
                bb[m] = *(const f32x4*)(b1 + m * 16 + kg * 4);
            }
            #pragma unroll
            for (int n = 0; n < 2; n++) {
                int rr = m0 + n * 16 + lr;
                int gr = base + rr;
                int env = gr / E2;
                int sr  = gr - env * E2;
                const ushort* sp_ = nfp + (size_t)(env * NNODES + snode[sr]) * NPAD;
                const ushort* dp_ = nfp + (size_t)(env * NNODES + dnode[sr]) * NPAD;
                f16x8 x0, x1;
                if (kg < 3) x0 = *(const f16x8*)(sp_ + kg * 8);
                else        x0 = *(const f16x8*)(dp_);
                if (kg < 2) x1 = *(const f16x8*)(dp_ + 8 + kg * 8);
                else        x1 = f16x8{(_Float16)0,(_Float16)0,(_Float16)0,(_Float16)0,
                                       (_Float16)0,(_Float16)0,(_Float16)0,(_Float16)0};
                f32x4 acc[4];
                #pragma unroll
                for (int m = 0; m < 4; m++) {
                    acc[m] = bb[m];
                    MFMA2(acc[m], wp[m][0], wp[m][1], x0, x1)
                }
                #pragma unroll
                for (int m = 0; m < 4; m++) STORE_H4(acc[m], m, rr)
            }
        }

        // ---- GEMM2 (swapped): W2 @ H1^T -> tanh -> H2 (in place) ----
        {
            f16x8 wp[4][2];
            f32x4 bb[4];
            #pragma unroll
            for (int m = 0; m < 4; m++) {
                #pragma unroll
                for (int kt = 0; kt < 2; kt++)
                    wp[m][kt] = *(const f16x8*)(W2p + (m * 16 + lr) * 64 + kt * 32 + kg * 8);
                bb[m] = *(const f32x4*)(b2 + m * 16 + kg * 4);
            }
            #pragma unroll
            for (int n = 0; n < 2; n++) {
                int rr = m0 + n * 16 + lr, sw = rr & 7;
                f16x8 x0 = *(const f16x8*)(Hp + rr * 64 + ((kg ^ sw) << 3));
                f16x8 x1 = *(const f16x8*)(Hp + rr * 64 + (((4 + kg) ^ sw) << 3));
                f32x4 acc[4];
                #pragma unroll
                for (int m = 0; m < 4; m++) {
                    acc[m] = bb[m];
                    MFMA2(acc[m], wp[m][0], wp[m][1], x0, x1)
                }
                #pragma unroll
                for (int m = 0; m < 4; m++) STORE_H4(acc[m], m, rr)
            }
        }

        // ---- GEMM3 (swapped) + segmented reduction ----
        {
            int gr_i  = base + m0 + i_;
            int env_i = gr_i / E2;
            int sr_i  = gr_i - env_i * E2;
            int key   = env_i * NNODES + snode[sr_i];        // full store row id

            f16x8 w3[2][2];
            #pragma unroll
            for (int m = 0; m < 2; m++)
                #pragma unroll
                for (int kt = 0; kt < 2; kt++)
                    w3[m][kt] = *(const f16x8*)(W3p + (m * 16 + lr) * 64 + kt * 32 + kg * 8);
            f32x4 bb0 = *(const f32x4*)(b3 + kg * 4);        // outs kg*4+r (<16)
            f32x4 bb1 = (kg == 0) ? *(const f32x4*)(b3 + 16) // outs 16..19
                                  : f32x4{0.f, 0.f, 0.f, 0.f};

            // load ALL B-frags first (msg overlay overwrites this wave's H rows)
            f16x8 xb[2][2];
            #pragma unroll
            for (int n = 0; n < 2; n++) {
                int rr = m0 + n * 16 + lr, sw = rr & 7;
                xb[n][0] = *(const f16x8*)(Hp + rr * 64 + ((kg ^ sw) << 3));
                xb[n][1] = *(const f16x8*)(Hp + rr * 64 + (((4 + kg) ^ sw) << 3));
            }
            f32x4 acc0[2], acc1[2];
            #pragma unroll
            for (int n = 0; n < 2; n++) {
                acc0[n] = bb0;
                MFMA2(acc0[n], w3[0][0], w3[0][1], xb[n][0], xb[n][1])
                acc1[n] = bb1;
                MFMA2(acc1[n], w3[1][0], w3[1][1], xb[n][0], xb[n][1])
            }

            // msg staging: [32 rows][stride 32 f32] per wave, b128 writes,
            // col-group swizzle g' = g ^ (row&7); key at group 5.
            int wbase = wave * 1024;                         // f32 words
            #pragma unroll
            for (int n = 0; n < 2; n++) {
                int row = n * 16 + lr;
                int g0 = kg ^ (row & 7);
                *(f32x4*)(msgf + wbase + row * 32 + (g0 << 2)) = acc0[n];
                if (kg == 0) {
                    int g1 = 4 ^ (row & 7);
                    *(f32x4*)(msgf + wbase + row * 32 + (g1 << 2)) = acc1[n];
                }
            }
            if (lane < 32) msgi[wbase + i_ * 32 + ((5 ^ (i_ & 7)) << 2)] = key;

            // segment-boundary flags (FULL exec: shfl/ballot legal here)
            int nxt = __shfl_down(key, 1);
            bool flag = (i_ == 31) || (key != nxt);
            unsigned fm = (unsigned)__ballot(flag);          // bits 0..31 valid

            if (lane < EFEAT) {
                int c = lane, g = c >> 2, o = c & 3;
                float sum = 0.f;
                for (int i = 0; i < 32; i++) {
                    sum += msgf[wbase + i * 32 + ((g ^ (i & 7)) << 2) + o];
                    if ((fm >> i) & 1u) {
                        int curk = msgi[wbase + i * 32 + ((5 ^ (i & 7)) << 2)];
                        atomicAdd(store + (size_t)curk * EFEAT + c, sum);
                        sum = 0.f;
                    }
                }
            }
        }
    }
#undef STORE_H4
#undef MFMA2
}

// GRU single step per (env,node); emits f32 nf AND next iteration's fp16 row.
// Also ZEROES its store row after reading (replaces the per-iteration memset).
__global__ __launch_bounds__(256) void gru_kernel(
    float* __restrict__ store,
    const float* __restrict__ Wih, const float* __restrict__ bih,
    const float* __restrict__ Whh, const float* __restrict__ bhh,
    float* __restrict__ nf,
    ushort* __restrict__ nfp)
{
    int gid = blockIdx.x * blockDim.x + threadIdx.x;
    const int total = NENV * NNODES;
    if (gid >= total) return;

    float*       s = store + (size_t)gid * EFEAT;
    float*       h = nf    + (size_t)gid * NFEAT;
    ushort*     ph = nfp   + (size_t)gid * NPAD;

    float sv[EFEAT], hv[NFEAT];
    #pragma unroll
    for (int k = 0; k < EFEAT; k++) sv[k] = s[k];
    #pragma unroll
    for (int k = 0; k < NFEAT; k++) hv[k] = h[k];

    // zero this node's store row for the next iteration (5 x float4 = 80 B)
    {
        float4 z = make_float4(0.f, 0.f, 0.f, 0.f);
        #pragma unroll
        for (int q = 0; q < 5; q++) *(float4*)(s + q * 4) = z;
    }

    for (int t = 0; t < NFEAT; t++) {
        float ir = bih[t],            hr = bhh[t];
        float iz = bih[NFEAT + t],    hz = bhh[NFEAT + t];
        float in_ = bih[2*NFEAT + t], hn = bhh[2*NFEAT + t];
        const float* wr = Wih + t * EFEAT;
        const float* wz = Wih + (NFEAT + t) * EFEAT;
        const float* wn = Wih + (2*NFEAT + t) * EFEAT;
        #pragma unroll
        for (int k = 0; k < EFEAT; k++) {
            ir  = fmaf(sv[k], wr[k], ir);
            iz  = fmaf(sv[k], wz[k], iz);
            in_ = fmaf(sv[k], wn[k], in_);
        }
        const float* vr = Whh + t * NFEAT;
        const float* vz = Whh + (NFEAT + t) * NFEAT;
        const float* vn = Whh + (2*NFEAT + t) * NFEAT;
        #pragma unroll
        for (int k = 0; k < NFEAT; k++) {
            hr = fmaf(hv[k], vr[k], hr);
            hz = fmaf(hv[k], vz[k], hz);
            hn = fmaf(hv[k], vn[k], hn);
        }
        float r = fast_sigmoid(ir + hr);
        float z = fast_sigmoid(iz + hz);
        float n = fast_tanh(in_ + r * hn);
        float hw = (1.f - z) * n + z * hv[t];
        h[t] = hw;
        ph[t] = f2h(hw);
    }
    *(uint2*)(ph + NFEAT) = make_uint2(0u, 0u);
}

extern "C" void kernel_launch(void* const* d_in, const int* in_sizes, int n_in,
                              void* d_out, int out_size, void* d_ws, size_t ws_size,
                              hipStream_t stream) {
    const float* nf_in = (const float*)d_in[0];
    const int*   edges = (const int*)d_in[1];
    const float* W1 = (const float*)d_in[2];
    const float* b1 = (const float*)d_in[3];
    const float* W2 = (const float*)d_in[4];
    const float* b2 = (const float*)d_in[5];
    const float* W3 = (const float*)d_in[6];
    const float* b3 = (const float*)d_in[7];
    const float* Wih = (const float*)d_in[8];
    const float* Whh = (const float*)d_in[9];
    const float* bih = (const float*)d_in[10];
    const float* bhh = (const float*)d_in[11];

    float* nf    = (float*)d_out;
    float* store = (float*)d_ws;
    const size_t nf_bytes    = (size_t)NENV * NNODES * NFEAT * sizeof(float);
    const size_t store_bytes = (size_t)NENV * NNODES * EFEAT * sizeof(float);
    // ws layout: store | W fp16 | nfp | cnt | cursor | snode | dnode  (~11 MB)
    ushort* W1p = (ushort*)((char*)d_ws + store_bytes);
    ushort* W2p = W1p + 64 * 64;
    ushort* W3p = W2p + 64 * 64;
    ushort* nfp = W3p + 32 * 64;
    int* cnt    = (int*)(nfp + (size_t)NENV * NNODES * NPAD);
    int* cursor = cnt + NNODES;
    int* snode  = cursor + NNODES;
    int* dnode  = snode + E2;

    // --- once per launch: weights, initial conversion, edge grouping by src ---
    prep_weights<<<16, 256, 0, stream>>>(W1, W2, W3, W1p, W2p, W3p);
    conv_nf<<<(NENV * NNODES + 255) / 256, 256, 0, stream>>>(nf_in, nfp);
    hipMemcpyAsync(nf, nf_in, nf_bytes, hipMemcpyDeviceToDevice, stream);
    hipMemsetAsync(cnt, 0, NNODES * sizeof(int), stream);
    hipMemsetAsync(store, 0, store_bytes, stream);        // once; GRU re-zeros after
    hist_kernel<<<(E2 + 255) / 256, 256, 0, stream>>>(edges, cnt);
    scan_kernel<<<1, 256, 0, stream>>>(cnt, cursor);
    scatter_kernel<<<(E2 + 255) / 256, 256, 0, stream>>>(edges, cursor, snode, dnode);

    const int edge_blocks = (NENV * E2) / SPAN;           // 6250, exact
    dim3 grid_n((NENV * NNODES + 255) / 256);

    for (int it = 0; it < ITERS; it++) {
        edge_mlp_mfma<<<edge_blocks, THREADS, 0, stream>>>(nfp, snode, dnode,
                                                           W1p, W2p, W3p,
                                                           b1, b2, b3, store);
        gru_kernel<<<grid_n, 256, 0, stream>>>(store, Wih, bih, Whh, bhh, nf, nfp);
    }
}

// Round 22
// 556.800 us; speedup vs baseline: 3.2126x; 1.1011x over previous
//
#include <hip/hip_runtime.h>

#define NFEAT 20
#define EFEAT 20
#define HID   64
#define NENV  16
#define NNODES 5000
#define NEDGES 50000
#define E2 (2*NEDGES)          // 100000 directed edges
#define ITERS 3
#define ROWS 64                // edge rows per block
#define THREADS 128            // 2 waves; wave w owns rows [w*32, w*32+32)
#define NPAD 24                // padded per-node fp16 row (20 + 4 junk) = 3 x 8-chunks

typedef __attribute__((ext_vector_type(8))) _Float16 f16x8;
typedef __attribute__((ext_vector_type(2))) __fp16  h16x2;   // builtin return type
typedef __attribute__((ext_vector_type(4))) float f32x4;

__device__ __forceinline__ ushort f2h(float f) {   // f32 -> fp16 RNE
    _Float16 h = (_Float16)f;
    return *(ushort*)&h;
}
__device__ __forceinline__ unsigned pk2h(float a, float b) {  // 2xf32 -> packed fp16 (RTZ)
    h16x2 p = __builtin_amdgcn_cvt_pkrtz(a, b);
    return *(unsigned*)&p;
}
// tanh = 1 - 2/(exp(2x)+1); exact limits at +-inf, no clamps. ~5 VALU ops.
__device__ __forceinline__ float fast_tanh(float x) {
    float e = __builtin_exp2f(x * 2.8853900817779268f);   // exp(2x)
    float r = __builtin_amdgcn_rcpf(e + 1.f);
    return fmaf(-2.f, r, 1.f);
}
__device__ __forceinline__ float fast_sigmoid(float x) {
    float e = __builtin_exp2f(x * -1.4426950408889634f);  // exp(-x)
    return __builtin_amdgcn_rcpf(1.f + e);
}

// ---------- edge preprocessing: group directed edges by src (once/launch) ----------
__global__ __launch_bounds__(256) void hist_kernel(const int* __restrict__ edges,
                                                   int* __restrict__ cnt) {
    int e = blockIdx.x * 256 + threadIdx.x;
    if (e < E2) atomicAdd(&cnt[edges[e]], 1);
}

__global__ __launch_bounds__(256) void scan_kernel(const int* __restrict__ cnt,
                                                   int* __restrict__ cursor) {
    __shared__ int part[256];
    int t = threadIdx.x;
    int local[20]; int s = 0;
    int base = t * 20;                      // 256*20 = 5120 >= 5000
    #pragma unroll
    for (int i = 0; i < 20; i++) {
        int idx = base + i;
        int v = (idx < NNODES) ? cnt[idx] : 0;
        local[i] = s; s += v;
    }
    part[t] = s;
    __syncthreads();
    for (int d = 1; d < 256; d <<= 1) {     // Hillis-Steele inclusive scan
        int v = (t >= d) ? part[t - d] : 0;
        __syncthreads();
        part[t] += v;
        __syncthreads();
    }
    int excl = part[t] - s;
    #pragma unroll
    for (int i = 0; i < 20; i++) {
        int idx = base + i;
        if (idx < NNODES) cursor[idx] = excl + local[i];
    }
}

// emits src-sorted node-id arrays: snode[pos], dnode[pos] (shared by all envs)
__global__ __launch_bounds__(256) void scatter_kernel(const int* __restrict__ edges,
                                                      int* __restrict__ cursor,
                                                      int* __restrict__ snode,
                                                      int* __restrict__ dnode) {
    int e = blockIdx.x * 256 + threadIdx.x;
    if (e < E2) {
        int s = edges[e];
        int di = e + NEDGES; if (di >= E2) di -= E2;
        int d = edges[di];
        int pos = atomicAdd(&cursor[s], 1);
        snode[pos] = s;
        dnode[pos] = d;
    }
}

// Weights -> fp16, layout [out][k], K padded to 64. Grid-stride (16 blocks).
// W1 K-layout matches padded X rows: k<20 = src feats, 24<=k<44 = dst feats, else 0.
__global__ __launch_bounds__(256) void prep_weights(
    const float* __restrict__ W1, const float* __restrict__ W2,
    const float* __restrict__ W3,
    ushort* __restrict__ W1p, ushort* __restrict__ W2p,
    ushort* __restrict__ W3p) {
    int stride = gridDim.x * 256;
    int t0 = blockIdx.x * 256 + threadIdx.x;
    for (int i = t0; i < 64 * 64; i += stride) {
        int n = i >> 6, k = i & 63;
        float v = 0.f;
        if (k < NFEAT)                          v = W1[n * (2 * NFEAT) + k];
        else if (k >= NPAD && k < NPAD + NFEAT) v = W1[n * (2 * NFEAT) + NFEAT + (k - NPAD)];
        W1p[i] = f2h(v);
    }
    for (int i = t0; i < 64 * 64; i += stride)
        W2p[i] = f2h(W2[i]);
    for (int i = t0; i < 32 * 64; i += stride) {
        int n = i >> 6, k = i & 63;
        W3p[i] = (n < EFEAT) ? f2h(W3[n * HID + k]) : (ushort)0;
    }
}

// Initial per-node fp16 conversion (iteration 0); later iters from gru_kernel.
__global__ __launch_bounds__(256) void conv_nf(const float* __restrict__ nf,
                                               ushort* __restrict__ nfp) {
    int gid = blockIdx.x * 256 + threadIdx.x;
    if (gid >= NENV * NNODES) return;
    const float* p = nf + (size_t)gid * NFEAT;
    ushort* ph = nfp + (size_t)gid * NPAD;
    #pragma unroll
    for (int k = 0; k < NFEAT; k++) ph[k] = f2h(p[k]);
    *(uint2*)(ph + NFEAT) = make_uint2(0u, 0u);         // zero pad cols 20..23
}

// 64 SORTED edge-rows/block, 2 waves, wave w owns rows [w*32,w*32+32) — all
// LDS traffic wave-local => NO barriers. 8 KB LDS (fp16 H plane / msg overlay).
// SWAPPED MFMA orientation: A = W[out][k], B = X^T -> D[out][edge-row].
// Lane owns 4 CONSECUTIVE outs of one row => epilogue packs via cvt_pkrtz into
// ds_write_b64 (H layers) / b128 f32x4 (GEMM3 msgs). Segmented scan over the
// per-wave LDS msg slice -> ~1 coalesced atomicAdd batch per (segment).
// Keys via LDS (no shfl in divergent code). [R17 terminal configuration]
__global__ __launch_bounds__(THREADS) void edge_mlp_mfma(
    const ushort* __restrict__ nfp,
    const int*   __restrict__ snode, const int* __restrict__ dnode,
    const ushort* __restrict__ W1p, const ushort* __restrict__ W2p,
    const ushort* __restrict__ W3p,
    const float* __restrict__ b1, const float* __restrict__ b2,
    const float* __restrict__ b3,
    float* __restrict__ store)
{
    __shared__ ushort smem16[4096];               // 8 KB
    ushort* Hp = smem16;                          // H plane: [64 rows][64 cols] fp16, swizzled
    float*  msgf = (float*)smem16;                // GEMM3 overlay, per-wave 4 KB slice
    int*    msgi = (int*)smem16;                  // int view (keys)

    const int tid  = threadIdx.x;
    const int wave = tid >> 6;
    const int lane = tid & 63;
    const int lr   = lane & 15;      // A-row(=out) / B-col(=edge-row) in tile; C-col
    const int kg   = lane >> 4;      // k-group for A/B; C row-group (out-group)
    const int m0   = wave * 32;

#define MFMA2(acc, w0, w1, x0, x1)                                                  \
    acc = __builtin_amdgcn_mfma_f32_16x16x32_f16(w0, x0, acc, 0, 0, 0);             \
    acc = __builtin_amdgcn_mfma_f32_16x16x32_f16(w1, x1, acc, 0, 0, 0);

    // packed epilogue: 4 outs (m*16+kg*4+r) of row rr -> one b64 write
#define STORE_H4(accv, m_, rr_)                                                     \
    {                                                                               \
        float t0 = fast_tanh(accv[0]), t1 = fast_tanh(accv[1]);                     \
        float t2 = fast_tanh(accv[2]), t3 = fast_tanh(accv[3]);                     \
        unsigned p01 = pk2h(t0, t1), p23 = pk2h(t2, t3);                            \
        int c8 = (m_) * 2 + (kg >> 1);                                              \
        int idx = (rr_) * 64 + ((c8 ^ ((rr_) & 7)) << 3) + ((kg & 1) << 2);         \
        *(uint2*)(Hp + idx) = make_uint2(p01, p23);                                 \
    }

    // ---- GEMM1 (swapped): W1 @ X^T -> tanh -> H1[edge-row][out] (LDS) ----
    {
        f16x8 wp[4][2];
        f32x4 bb[4];
        #pragma unroll
        for (int m = 0; m < 4; m++) {
            #pragma unroll
            for (int kt = 0; kt < 2; kt++)
                wp[m][kt] = *(const f16x8*)(W1p + (m * 16 + lr) * 64 + kt * 32 + kg * 8);
            bb[m] = *(const f32x4*)(b1 + m * 16 + kg * 4);
        }
        #pragma unroll
        for (int n = 0; n < 2; n++) {
            int rr = m0 + n * 16 + lr;
            int gr = blockIdx.x * ROWS + rr;
            int env = gr / E2;
            int sr  = gr - env * E2;
            const ushort* sp_ = nfp + (size_t)(env * NNODES + snode[sr]) * NPAD;
            const ushort* dp_ = nfp + (size_t)(env * NNODES + dnode[sr]) * NPAD;
            f16x8 x0, x1;
            if (kg < 3) x0 = *(const f16x8*)(sp_ + kg * 8);
            else        x0 = *(const f16x8*)(dp_);
            if (kg < 2) x1 = *(const f16x8*)(dp_ + 8 + kg * 8);
            else        x1 = f16x8{(_Float16)0,(_Float16)0,(_Float16)0,(_Float16)0,
                                   (_Float16)0,(_Float16)0,(_Float16)0,(_Float16)0};
            f32x4 acc[4];
            #pragma unroll
            for (int m = 0; m < 4; m++) {
                acc[m] = bb[m];
                MFMA2(acc[m], wp[m][0], wp[m][1], x0, x1)
            }
            #pragma unroll
            for (int m = 0; m < 4; m++) STORE_H4(acc[m], m, rr)
        }
    }

    // ---- GEMM2 (swapped): W2 @ H1^T -> tanh -> H2 (in place, per 16-row range) ----
    {
        f16x8 wp[4][2];
        f32x4 bb[4];
        #pragma unroll
        for (int m = 0; m < 4; m++) {
            #pragma unroll
            for (int kt = 0; kt < 2; kt++)
                wp[m][kt] = *(const f16x8*)(W2p + (m * 16 + lr) * 64 + kt * 32 + kg * 8);
            bb[m] = *(const f32x4*)(b2 + m * 16 + kg * 4);
        }
        #pragma unroll
        for (int n = 0; n < 2; n++) {
            int rr = m0 + n * 16 + lr, sw = rr & 7;
            f16x8 x0 = *(const f16x8*)(Hp + rr * 64 + ((kg ^ sw) << 3));
            f16x8 x1 = *(const f16x8*)(Hp + rr * 64 + (((4 + kg) ^ sw) << 3));
            f32x4 acc[4];
            #pragma unroll
            for (int m = 0; m < 4; m++) {
                acc[m] = bb[m];
                MFMA2(acc[m], wp[m][0], wp[m][1], x0, x1)
            }
            #pragma unroll
            for (int m = 0; m < 4; m++) STORE_H4(acc[m], m, rr)
        }
    }

    // ---- GEMM3 (swapped) + segmented reduction ----
    {
        int i_ = lane & 31;
        int gr_i  = blockIdx.x * ROWS + m0 + i_;
        int env_i = gr_i / E2;
        int sr_i  = gr_i - env_i * E2;
        int key   = env_i * NNODES + snode[sr_i];            // full store row id

        f16x8 w3[2][2];
        #pragma unroll
        for (int m = 0; m < 2; m++)
            #pragma unroll
            for (int kt = 0; kt < 2; kt++)
                w3[m][kt] = *(const f16x8*)(W3p + (m * 16 + lr) * 64 + kt * 32 + kg * 8);
        f32x4 bb0 = *(const f32x4*)(b3 + kg * 4);            // outs kg*4+r (<16)
        f32x4 bb1 = (kg == 0) ? *(const f32x4*)(b3 + 16)     // outs 16..19
                              : f32x4{0.f, 0.f, 0.f, 0.f};

        // load ALL B-frags first (msg overlay overwrites this wave's H rows)
        f16x8 xb[2][2];
        #pragma unroll
        for (int n = 0; n < 2; n++) {
            int rr = m0 + n * 16 + lr, sw = rr & 7;
            xb[n][0] = *(const f16x8*)(Hp + rr * 64 + ((kg ^ sw) << 3));
            xb[n][1] = *(const f16x8*)(Hp + rr * 64 + (((4 + kg) ^ sw) << 3));
        }
        f32x4 acc0[2], acc1[2];
        #pragma unroll
        for (int n = 0; n < 2; n++) {
            acc0[n] = bb0;
            MFMA2(acc0[n], w3[0][0], w3[0][1], xb[n][0], xb[n][1])
            acc1[n] = bb1;
            MFMA2(acc1[n], w3[1][0], w3[1][1], xb[n][0], xb[n][1])
        }

        // msg staging: [32 rows][stride 32 f32] per wave, b128 writes,
        // col-group swizzle g' = g ^ (row&7); key at group 5.
        int wbase = wave * 1024;                             // f32 words
        #pragma unroll
        for (int n = 0; n < 2; n++) {
            int row = n * 16 + lr;
            int g0 = kg ^ (row & 7);
            *(f32x4*)(msgf + wbase + row * 32 + (g0 << 2)) = acc0[n];
            if (kg == 0) {
                int g1 = 4 ^ (row & 7);
                *(f32x4*)(msgf + wbase + row * 32 + (g1 << 2)) = acc1[n];
            }
        }
        if (lane < 32) msgi[wbase + i_ * 32 + ((5 ^ (i_ & 7)) << 2)] = key;

        // segment-boundary flags (FULL exec: shfl/ballot legal here)
        int nxt = __shfl_down(key, 1);
        bool flag = (i_ == 31) || (key != nxt);
        unsigned fm = (unsigned)__ballot(flag);              // bits 0..31 valid

        if (lane < EFEAT) {
            int c = lane, g = c >> 2, o = c & 3;
            float sum = 0.f;
            for (int i = 0; i < 32; i++) {
                sum += msgf[wbase + i * 32 + ((g ^ (i & 7)) << 2) + o];
                if ((fm >> i) & 1u) {
                    int curk = msgi[wbase + i * 32 + ((5 ^ (i & 7)) << 2)];
                    atomicAdd(store + (size_t)curk * EFEAT + c, sum);
                    sum = 0.f;
                }
            }
        }
    }
#undef STORE_H4
#undef MFMA2
}

// GRU single step per (env,node); emits f32 nf AND next iteration's fp16 row.
// Also ZEROES its store row after reading (replaces the per-iteration memset:
// each thread exclusively owns row `node` of store; next edge dispatch only
// runs after this kernel completes, so it sees a zeroed buffer).
__global__ __launch_bounds__(256) void gru_kernel(
    float* __restrict__ store,
    const float* __restrict__ Wih, const float* __restrict__ bih,
    const float* __restrict__ Whh, const float* __restrict__ bhh,
    float* __restrict__ nf,
    ushort* __restrict__ nfp)
{
    int gid = blockIdx.x * blockDim.x + threadIdx.x;
    const int total = NENV * NNODES;
    if (gid >= total) return;

    float*       s = store + (size_t)gid * EFEAT;
    float*       h = nf    + (size_t)gid * NFEAT;
    ushort*     ph = nfp   + (size_t)gid * NPAD;

    float sv[EFEAT], hv[NFEAT];
    #pragma unroll
    for (int k = 0; k < EFEAT; k++) sv[k] = s[k];
    #pragma unroll
    for (int k = 0; k < NFEAT; k++) hv[k] = h[k];

    // zero this node's store row for the next iteration (5 x float4 = 80 B)
    {
        float4 z = make_float4(0.f, 0.f, 0.f, 0.f);
        #pragma unroll
        for (int q = 0; q < 5; q++) *(float4*)(s + q * 4) = z;
    }

    for (int t = 0; t < NFEAT; t++) {
        float ir = bih[t],            hr = bhh[t];
        float iz = bih[NFEAT + t],    hz = bhh[NFEAT + t];
        float in_ = bih[2*NFEAT + t], hn = bhh[2*NFEAT + t];
        const float* wr = Wih + t * EFEAT;
        const float* wz = Wih + (NFEAT + t) * EFEAT;
        const float* wn = Wih + (2*NFEAT + t) * EFEAT;
        #pragma unroll
        for (int k = 0; k < EFEAT; k++) {
            ir  = fmaf(sv[k], wr[k], ir);
            iz  = fmaf(sv[k], wz[k], iz);
            in_ = fmaf(sv[k], wn[k], in_);
        }
        const float* vr = Whh + t * NFEAT;
        const float* vz = Whh + (NFEAT + t) * NFEAT;
        const float* vn = Whh + (2*NFEAT + t) * NFEAT;
        #pragma unroll
        for (int k = 0; k < NFEAT; k++) {
            hr = fmaf(hv[k], vr[k], hr);
            hz = fmaf(hv[k], vz[k], hz);
            hn = fmaf(hv[k], vn[k], hn);
        }
        float r = fast_sigmoid(ir + hr);
        float z = fast_sigmoid(iz + hz);
        float n = fast_tanh(in_ + r * hn);
        float hw = (1.f - z) * n + z * hv[t];
        h[t] = hw;
        ph[t] = f2h(hw);
    }
    *(uint2*)(ph + NFEAT) = make_uint2(0u, 0u);
}

extern "C" void kernel_launch(void* const* d_in, const int* in_sizes, int n_in,
                              void* d_out, int out_size, void* d_ws, size_t ws_size,
                              hipStream_t stream) {
    const float* nf_in = (const float*)d_in[0];
    const int*   edges = (const int*)d_in[1];
    const float* W1 = (const float*)d_in[2];
    const float* b1 = (const float*)d_in[3];
    const float* W2 = (const float*)d_in[4];
    const float* b2 = (const float*)d_in[5];
    const float* W3 = (const float*)d_in[6];
    const float* b3 = (const float*)d_in[7];
    const float* Wih = (const float*)d_in[8];
    const float* Whh = (const float*)d_in[9];
    const float* bih = (const float*)d_in[10];
    const float* bhh = (const float*)d_in[11];

    float* nf    = (float*)d_out;
    float* store = (float*)d_ws;
    const size_t nf_bytes    = (size_t)NENV * NNODES * NFEAT * sizeof(float);
    const size_t store_bytes = (size_t)NENV * NNODES * EFEAT * sizeof(float);
    // ws layout: store | W fp16 | nfp | cnt | cursor | snode | dnode  (~11 MB)
    ushort* W1p = (ushort*)((char*)d_ws + store_bytes);
    ushort* W2p = W1p + 64 * 64;
    ushort* W3p = W2p + 64 * 64;
    ushort* nfp = W3p + 32 * 64;
    int* cnt    = (int*)(nfp + (size_t)NENV * NNODES * NPAD);
    int* cursor = cnt + NNODES;
    int* snode  = cursor + NNODES;
    int* dnode  = snode + E2;

    // --- once per launch: weights, initial conversion, edge grouping by src ---
    prep_weights<<<16, 256, 0, stream>>>(W1, W2, W3, W1p, W2p, W3p);
    conv_nf<<<(NENV * NNODES + 255) / 256, 256, 0, stream>>>(nf_in, nfp);
    hipMemcpyAsync(nf, nf_in, nf_bytes, hipMemcpyDeviceToDevice, stream);
    hipMemsetAsync(cnt, 0, NNODES * sizeof(int), stream);
    hipMemsetAsync(store, 0, store_bytes, stream);        // once; GRU re-zeros after
    hist_kernel<<<(E2 + 255) / 256, 256, 0, stream>>>(edges, cnt);
    scan_kernel<<<1, 256, 0, stream>>>(cnt, cursor);
    scatter_kernel<<<(E2 + 255) / 256, 256, 0, stream>>>(edges, cursor, snode, dnode);

    const int edge_blocks = (NENV * E2) / ROWS;           // 25000, exact
    dim3 grid_n((NENV * NNODES + 255) / 256);

    for (int it = 0; it < ITERS; it++) {
        edge_mlp_mfma<<<edge_blocks, THREADS, 0, stream>>>(nfp, snode, dnode,
                                                           W1p, W2p, W3p,
                                                           b1, b2, b3, store);
        gru_kernel<<<grid_n, 256, 0, stream>>>(store, Wih, bih, Whh, bhh, nf, nfp);
    }
}